// Round 2
// baseline (209.733 us; speedup 1.0000x reference)
//
#include <hip/hip_runtime.h>

// LGA2 fused: out = LGA(LGA(x,f),f), radius=2 (25 taps), fp32.
// x: [N=2, C=64, H=256, W=512], f: [N, 25, H, W], out like x.
//
// Block: 256 threads = 16 rows x 16 strips (4 cols each) over a TEMP region
// of 16x64, which yields an OUTPUT tile of 12x60 (temp minus radius-2 border).
// X region staged in LDS: 20x68. temp lives only in LDS.
// Filters for each thread's fixed (row, 4-col strip) position are cached in
// registers fr[25][4] and reused across the 32-channel loop AND both passes.

#define TH 12
#define TW 60
#define SXS 76   // LDS row stride (dwords) for x region (20 x 68 used)
#define STS 76   // LDS row stride (dwords) for temp (16 x [2 guard + 64 + 2 guard])

__global__ __launch_bounds__(256, 3)
void lga2_fused(const float* __restrict__ x, const float* __restrict__ f,
                float* __restrict__ out,
                int N, int C, int H, int W, int CH_PER_BLK) {
    const int tid = threadIdx.x;
    const int r = tid >> 4;   // temp-region row 0..15
    const int s = tid & 15;   // 4-wide strip index 0..15
    const int bx = blockIdx.x;            // w tile
    const int by = blockIdx.y;            // h tile
    const int CGRP = C / CH_PER_BLK;      // 2
    const int n  = blockIdx.z / CGRP;
    const int cg = blockIdx.z % CGRP;
    const int oh0 = by * TH;
    const int ow0 = bx * TW;

    __shared__ float sx[20 * SXS];
    __shared__ float st[16 * STS];

    // zero temp guard columns (dwords 0,1,66,67 of each row) once
    if (tid < 64) {
        int zr = tid >> 2, q = tid & 3;
        int col = (q < 2) ? q : q + 64;   // 0,1,66,67
        st[zr * STS + col] = 0.0f;
    }

    // ---- filter registers: fr[tap][rr] at (gh_f, gwb+rr) ----
    const int gh_f = oh0 - 2 + r;          // this thread's temp/out row (global)
    const int gwb  = ow0 - 2 + 4 * s;      // strip's first global col
    const bool rowok = (gh_f >= 0) && (gh_f < H);
    float fr[25][4];
    #pragma unroll
    for (int t = 0; t < 25; ++t) {
        const float* fp = f + (((size_t)(n * 25 + t) * H + gh_f) * W) + gwb;
        #pragma unroll
        for (int rr = 0; rr < 4; ++rr) {
            const int gw = gwb + rr;
            fr[t][rr] = (rowok && gw >= 0 && gw < W) ? fp[rr] : 0.0f;
        }
    }

    const int c0 = cg * CH_PER_BLK;
    for (int cc = 0; cc < CH_PER_BLK; ++cc) {
        const int c = c0 + cc;
        const float* xc = x + (size_t)(n * C + c) * H * W;

        // ---- stage x region 20x68 into LDS (vec4, zero-padded) ----
        #pragma unroll
        for (int it = 0; it < 2; ++it) {
            const int idx = tid + it * 256;
            if (idx < 340) {                       // 20 rows * 17 vec4
                const int row = idx / 17;
                const int v   = idx - row * 17;
                const int gh  = oh0 - 4 + row;
                const int gc  = ow0 - 4 + v * 4;
                float4 val = make_float4(0.f, 0.f, 0.f, 0.f);
                if (gh >= 0 && gh < H && gc >= 0 && gc + 3 < W)
                    val = *(const float4*)(xc + (size_t)gh * W + gc);
                *(float4*)&sx[row * SXS + v * 4] = val;
            }
        }
        __syncthreads();   // sx ready; also fences prev iteration's pass2

        // ---- pass 1: temp at (r, 4s..4s+3) ----
        float a0 = 0.f, a1 = 0.f, a2 = 0.f, a3 = 0.f;
        #pragma unroll
        for (int i = 0; i < 5; ++i) {
            const float* xr = &sx[(r + i) * SXS + 4 * s];
            const float4 xa = *(const float4*)xr;
            const float4 xb = *(const float4*)(xr + 4);
            const float xv[8] = {xa.x, xa.y, xa.z, xa.w, xb.x, xb.y, xb.z, xb.w};
            #pragma unroll
            for (int j = 0; j < 5; ++j) {
                a0 = fmaf(fr[i * 5 + j][0], xv[j + 0], a0);
                a1 = fmaf(fr[i * 5 + j][1], xv[j + 1], a1);
                a2 = fmaf(fr[i * 5 + j][2], xv[j + 2], a2);
                a3 = fmaf(fr[i * 5 + j][3], xv[j + 3], a3);
            }
        }
        // OOB (f=0, x=0) positions produced 0 — exactly the zero-pad semantics.
        *(float2*)&st[r * STS + 2 + 4 * s] = make_float2(a0, a1);
        *(float2*)&st[r * STS + 4 + 4 * s] = make_float2(a2, a3);
        __syncthreads();   // temp ready; sx free for next staging

        // ---- pass 2: out at interior of temp region ----
        if (r >= 2 && r < 14) {
            float o0 = 0.f, o1 = 0.f, o2 = 0.f, o3 = 0.f;
            #pragma unroll
            for (int i = 0; i < 5; ++i) {
                const float* tr_ = &st[(r - 2 + i) * STS + 4 * s];
                const float4 ta = *(const float4*)tr_;
                const float4 tb = *(const float4*)(tr_ + 4);
                const float tv[8] = {ta.x, ta.y, ta.z, ta.w, tb.x, tb.y, tb.z, tb.w};
                #pragma unroll
                for (int j = 0; j < 5; ++j) {
                    o0 = fmaf(fr[i * 5 + j][0], tv[j + 0], o0);
                    o1 = fmaf(fr[i * 5 + j][1], tv[j + 1], o1);
                    o2 = fmaf(fr[i * 5 + j][2], tv[j + 2], o2);
                    o3 = fmaf(fr[i * 5 + j][3], tv[j + 3], o3);
                }
            }
            if (gh_f < H) {   // gh_f >= 0 guaranteed for r >= 2
                float* op = out + ((size_t)(n * C + c) * H + gh_f) * W + gwb;
                // pair (cols gwb, gwb+1): interior iff s>=1
                if (s >= 1 && gwb + 1 < W)
                    *(float2*)op = make_float2(o0, o1);
                // pair (cols gwb+2, gwb+3): interior iff s<=14
                if (s <= 14 && gwb + 3 < W)
                    *(float2*)(op + 2) = make_float2(o2, o3);
            }
        }
        // next iteration's __syncthreads (after staging) fences st reads
    }
}

extern "C" void kernel_launch(void* const* d_in, const int* in_sizes, int n_in,
                              void* d_out, int out_size, void* d_ws, size_t ws_size,
                              hipStream_t stream) {
    const float* x = (const float*)d_in[0];
    const float* f = (const float*)d_in[1];
    float* out = (float*)d_out;

    const int N = 2, C = 64, H = 256, W = 512;
    const int CH_PER_BLK = 32;                 // 2 channel groups
    const int CGRP = C / CH_PER_BLK;

    dim3 grid((W + TW - 1) / TW,               // 9
              (H + TH - 1) / TH,               // 22
              N * CGRP);                       // 4
    lga2_fused<<<grid, 256, 0, stream>>>(x, f, out, N, C, H, W, CH_PER_BLK);
}

// Round 3
// 143.891 us; speedup vs baseline: 1.4576x; 1.4576x over previous
//
#include <hip/hip_runtime.h>

// LGA2 fused: out = LGA(LGA(x,f),f), radius=2 (25 taps), fp32.
// x: [N=2, C=64, H=256, W=512], f: [N, 25, H, W], out like x.
//
// R3 changes vs R2:
//  - 64-col-aligned OUTPUT tiles (11x64) -> no partial-cacheline write amp.
//    Temp region 15x68 covered by 255 threads = 15 rows x 17 strips of 4 cols.
//  - Filter regs fr[25][4] PINNED via asm("" : "+v") so the RA cannot
//    rematerialize them as per-channel global reloads (R2: VGPR=84 < 100).
//  - Double-buffered sx + software prefetch: channel c+1's global loads are
//    issued before pass1 of channel c, written to the other LDS buffer after
//    pass2 -> HBM latency hidden under compute.

#define TROWS 15   // temp rows per block
#define OH 11      // output rows per block
#define OW 64      // output cols per block (64B*4-aligned)
#define SXROWS 19  // x region rows (TROWS + 4)
#define SXS 76     // LDS row stride in dwords (72 used + 4 pad, quad-shift 3)
#define STS 76     // temp row stride ([2 guard][68 temp][2 guard] + 4 pad)

__global__ __launch_bounds__(256, 3)
void lga2_fused(const float* __restrict__ x, const float* __restrict__ f,
                float* __restrict__ out,
                int N, int C, int H, int W, int CPB) {
    const int tid = threadIdx.x;
    const int r = tid / 17;          // temp row 0..15 (15 => inactive)
    const int s = tid - r * 17;      // strip 0..16 (4 cols each)
    const bool active = (r < TROWS);

    const int oh0 = blockIdx.y * OH;
    const int ow0 = blockIdx.x * OW;
    const int CG = C / CPB;
    const int n  = blockIdx.z / CG;
    const int cg = blockIdx.z % CG;
    const int c0 = cg * CPB;

    __shared__ float sx[2 * SXROWS * SXS];
    __shared__ float st[TROWS * STS];

    // zero temp guard columns (dwords 0,1,70,71 of each temp row) once
    if (tid < 4 * TROWS) {
        int zr = tid >> 2, q = tid & 3;
        int col = (q < 2) ? q : q + 68;    // 0,1,70,71
        st[zr * STS + col] = 0.0f;
    }

    // ---- filter registers: fr[tap][rr] at (gh_f, gwb+rr), pinned ----
    const int gh_f = oh0 - 2 + r;          // this thread's temp/out row
    const int gwb  = ow0 - 2 + 4 * s;      // strip's first global col
    const bool rowok = active && (gh_f >= 0) && (gh_f < H);
    float fr[25][4];
    #pragma unroll
    for (int t = 0; t < 25; ++t) {
        const int ghc = rowok ? gh_f : 0;
        const float* fp = f + (((size_t)(n * 25 + t) * H + ghc) * W);
        #pragma unroll
        for (int rr = 0; rr < 4; ++rr) {
            const int gw = gwb + rr;
            fr[t][rr] = (rowok && gw >= 0 && gw < W) ? fp[gw] : 0.0f;
            asm volatile("" : "+v"(fr[t][rr]));   // pin: no remat/reload
        }
    }

    // ---- staging geometry: 19 rows x 18 float4 = 342 vec4 loads ----
    const int i0r = tid / 18, i0v = tid - i0r * 18;
    const int i1  = tid + 256;
    const int i1r = i1 / 18, i1v = i1 - i1r * 18;
    const bool has1 = (tid < 342 - 256);
    const int g0h = oh0 - 4 + i0r, g0c = ow0 - 4 + i0v * 4;
    const int g1h = oh0 - 4 + i1r, g1c = ow0 - 4 + i1v * 4;
    const bool v0 = (g0h >= 0) && (g0h < H) && (g0c >= 0) && (g0c <= W - 4);
    const bool v1 = has1 && (g1h >= 0) && (g1h < H) && (g1c >= 0) && (g1c <= W - 4);
    const size_t o0 = (size_t)(v0 ? g0h : 0) * W + (v0 ? g0c : 0);
    const size_t o1 = (size_t)(v1 ? g1h : 0) * W + (v1 ? g1c : 0);
    const int l0 = i0r * SXS + i0v * 4;
    const int l1 = i1r * SXS + i1v * 4;

    const float4 zero4 = make_float4(0.f, 0.f, 0.f, 0.f);
    const float* xc0 = x + (size_t)(n * C + c0) * H * W;
    const size_t HW = (size_t)H * W;

    // prologue: stage channel c0 into buffer 0
    {
        float4 p0 = v0 ? *(const float4*)(xc0 + o0) : zero4;
        *(float4*)&sx[l0] = p0;
        if (has1) {
            float4 p1v = v1 ? *(const float4*)(xc0 + o1) : zero4;
            *(float4*)&sx[l1] = p1v;
        }
    }
    __syncthreads();

    int cur = 0;
    for (int cc = 0; cc < CPB; ++cc) {
        // ---- issue prefetch for channel cc+1 (used after pass 2) ----
        float4 n0 = zero4, n1 = zero4;
        const bool pf = (cc + 1 < CPB);
        if (pf) {
            const float* xn = xc0 + (size_t)(cc + 1) * HW;
            if (v0) n0 = *(const float4*)(xn + o0);
            if (v1) n1 = *(const float4*)(xn + o1);
        }

        // ---- pass 1: temp at (r, 4s..4s+3) ----
        if (active) {
            const float* base = &sx[cur * (SXROWS * SXS)];
            float a0 = 0.f, a1 = 0.f, a2 = 0.f, a3 = 0.f;
            #pragma unroll
            for (int i = 0; i < 5; ++i) {
                const float* xr = &base[(r + i) * SXS + 4 * s];
                const float4 xa = *(const float4*)xr;
                const float4 xb = *(const float4*)(xr + 4);
                const float xv[8] = {xa.x, xa.y, xa.z, xa.w, xb.x, xb.y, xb.z, xb.w};
                #pragma unroll
                for (int j = 0; j < 5; ++j) {
                    a0 = fmaf(fr[i * 5 + j][0], xv[j + 0], a0);
                    a1 = fmaf(fr[i * 5 + j][1], xv[j + 1], a1);
                    a2 = fmaf(fr[i * 5 + j][2], xv[j + 2], a2);
                    a3 = fmaf(fr[i * 5 + j][3], xv[j + 3], a3);
                }
            }
            *(float2*)&st[r * STS + 2 + 4 * s] = make_float2(a0, a1);
            *(float2*)&st[r * STS + 4 + 4 * s] = make_float2(a2, a3);
        }
        __syncthreads();   // temp visible

        // ---- pass 2: out rows oh0..oh0+10, cols ow0..ow0+63 ----
        if (active && r >= 2 && r <= 12 && gh_f < H) {
            float o0a = 0.f, o1a = 0.f, o2a = 0.f, o3a = 0.f;
            #pragma unroll
            for (int i = 0; i < 5; ++i) {
                const float* tr_ = &st[(r - 2 + i) * STS + 4 * s];
                const float4 ta = *(const float4*)tr_;
                const float4 tb = *(const float4*)(tr_ + 4);
                const float tv[8] = {ta.x, ta.y, ta.z, ta.w, tb.x, tb.y, tb.z, tb.w};
                #pragma unroll
                for (int j = 0; j < 5; ++j) {
                    o0a = fmaf(fr[i * 5 + j][0], tv[j + 0], o0a);
                    o1a = fmaf(fr[i * 5 + j][1], tv[j + 1], o1a);
                    o2a = fmaf(fr[i * 5 + j][2], tv[j + 2], o2a);
                    o3a = fmaf(fr[i * 5 + j][3], tv[j + 3], o3a);
                }
            }
            float* op = out + ((size_t)(n * C + c0 + cc) * H + gh_f) * W + gwb;
            if (s >= 1)  *(float2*)op       = make_float2(o0a, o1a);  // cols 4s-2,4s-1
            if (s <= 15) *(float2*)(op + 2) = make_float2(o2a, o3a);  // cols 4s,4s+1
        }

        // ---- land prefetch into the other buffer ----
        if (pf) {
            float* d = &sx[(cur ^ 1) * (SXROWS * SXS)];
            *(float4*)&d[l0] = n0;
            if (has1) *(float4*)&d[l1] = n1;
        }
        __syncthreads();   // next sx ready; st reads done before next p1 write
        cur ^= 1;
    }
}

extern "C" void kernel_launch(void* const* d_in, const int* in_sizes, int n_in,
                              void* d_out, int out_size, void* d_ws, size_t ws_size,
                              hipStream_t stream) {
    const float* x = (const float*)d_in[0];
    const float* f = (const float*)d_in[1];
    float* out = (float*)d_out;

    const int N = 2, C = 64, H = 256, W = 512;
    const int CPB = 32;                        // channels per block
    const int CG = C / CPB;                    // 2

    dim3 grid(W / OW,                          // 8
              (H + OH - 1) / OH,               // 24
              N * CG);                         // 4  -> 768 blocks = 3/CU
    lga2_fused<<<grid, 256, 0, stream>>>(x, f, out, N, C, H, W, CPB);
}